// Round 1
// baseline (125.731 us; speedup 1.0000x reference)
//
#include <hip/hip_runtime.h>
#include <math.h>

// Problem constants (from setup_inputs)
constexpr int B   = 4;
constexpr int N   = 160;
constexpr int R   = 64;
constexpr int EMB = 128;
constexpr int HID = 128;
constexpr float EPS_LN  = 1e-5f;
constexpr float CLIP_LO = -0.999999f;   // -1.0 + 1e-6
constexpr float CLIP_HI =  0.999999f;   //  1.0 - 1e-6

// -------------------------------------------------------------------------
// Kernel 1: w[b,i,j] = sigmoid(sum_r rbf[b,i,j,r]*w_rad[r] + b_rad) * mask
// One wave (64 lanes) per output element; lane = r. Coalesced 256B/wave.
// -------------------------------------------------------------------------
__global__ __launch_bounds__(256) void radial_w_kernel(
    const float* __restrict__ rbf,
    const float* __restrict__ mask,
    const float* __restrict__ w_rad,
    const float* __restrict__ b_rad,
    float* __restrict__ w_out)
{
    const int wave = (blockIdx.x * blockDim.x + threadIdx.x) >> 6;
    const int lane = threadIdx.x & 63;
    if (wave >= B * N * N) return;

    float v = rbf[(size_t)wave * R + lane] * w_rad[lane];
    #pragma unroll
    for (int o = 32; o; o >>= 1) v += __shfl_xor(v, o);

    if (lane == 0) {
        float s   = v + b_rad[0];
        float sig = 1.0f / (1.0f + expf(-s));
        w_out[wave] = sig * mask[wave];
    }
}

// -------------------------------------------------------------------------
// Kernel 2: per (b,i): triple-sum aggregation over (j,k) pairs, then
// MLP (4 -> HID silu -> EMB) + LayerNorm. One 256-thread block per (b,i).
// -------------------------------------------------------------------------
__global__ __launch_bounds__(256) void agg_mlp_ln_kernel(
    const float* __restrict__ r_hat,
    const float* __restrict__ wv_g,
    const float* __restrict__ w1,
    const float* __restrict__ b1,
    const float* __restrict__ w2,
    const float* __restrict__ b2,
    const float* __restrict__ gamma,
    const float* __restrict__ beta,
    float* __restrict__ out)
{
    __shared__ float xs[N], ys[N], zs[N], wv[N];
    __shared__ float red[4 * 4];   // 4 waves x 4 accumulators
    __shared__ float hs[HID];
    __shared__ float red2[4];      // LN reductions (2 waves x 2 uses)

    const int bi  = blockIdx.x;    // 0 .. B*N-1
    const int tid = threadIdx.x;

    // Stage weights (160 floats) and unit vectors (160x3 floats) in LDS.
    if (tid < N) wv[tid] = wv_g[(size_t)bi * N + tid];
    const float* rh = r_hat + (size_t)bi * N * 3;
    for (int f = tid; f < N * 3; f += 256) {
        int j = f / 3, c = f - 3 * j;
        float val = rh[f];
        if (c == 0)      xs[j] = val;
        else if (c == 1) ys[j] = val;
        else             zs[j] = val;
    }
    __syncthreads();

    // Pair loop: 160*160 = 25600 pairs, 100 per thread.
    float a0 = 0.f, a1 = 0.f, a2 = 0.f, a3 = 0.f;
    for (int p = tid; p < N * N; p += 256) {
        int j = p / N, k = p - j * N;
        float ww = wv[j] * wv[k];
        float x  = xs[j] * xs[k] + ys[j] * ys[k] + zs[j] * zs[k];
        x = fminf(fmaxf(x, CLIP_LO), CLIP_HI);
        // Legendre recurrence (matches reference): n*Pn = (2n-1)x P_{n-1} - (n-1) P_{n-2}
        float p1 = x;
        float p2 = (3.0f * x * p1 - 1.0f) * 0.5f;
        float p3 = (5.0f * x * p2 - 2.0f * p1) / 3.0f;
        a0 += ww;
        a1 += ww * p1;
        a2 += ww * p2;
        a3 += ww * p3;
    }

    // Reduce the 4 accumulators across the block.
    #pragma unroll
    for (int o = 32; o; o >>= 1) {
        a0 += __shfl_xor(a0, o);
        a1 += __shfl_xor(a1, o);
        a2 += __shfl_xor(a2, o);
        a3 += __shfl_xor(a3, o);
    }
    const int wid = tid >> 6;
    if ((tid & 63) == 0) {
        red[wid * 4 + 0] = a0;
        red[wid * 4 + 1] = a1;
        red[wid * 4 + 2] = a2;
        red[wid * 4 + 3] = a3;
    }
    __syncthreads();

    // MLP layer 1: hid = silu(agg @ w1^T + b1), threads 0..127
    if (tid < HID) {
        float agg0 = red[0] + red[4] + red[8]  + red[12];
        float agg1 = red[1] + red[5] + red[9]  + red[13];
        float agg2 = red[2] + red[6] + red[10] + red[14];
        float agg3 = red[3] + red[7] + red[11] + red[15];
        float pre = b1[tid] + agg0 * w1[tid * 4 + 0] + agg1 * w1[tid * 4 + 1]
                            + agg2 * w1[tid * 4 + 2] + agg3 * w1[tid * 4 + 3];
        hs[tid] = pre / (1.0f + expf(-pre));   // silu = x * sigmoid(x)
    }
    __syncthreads();

    // MLP layer 2 + LayerNorm (threads 0..127; 2 waves)
    float acc = 0.f;
    if (tid < EMB) {
        acc = b2[tid];
        const float* w2r = w2 + (size_t)tid * HID;
        #pragma unroll 8
        for (int h = 0; h < HID; ++h) acc += hs[h] * w2r[h];
        float s = acc;
        #pragma unroll
        for (int o = 32; o; o >>= 1) s += __shfl_xor(s, o);
        if ((tid & 63) == 0) red2[tid >> 6] = s;
    }
    __syncthreads();

    const float mu = (red2[0] + red2[1]) * (1.0f / (float)EMB);
    const float d  = acc - mu;
    if (tid < EMB) {
        float s2 = d * d;
        #pragma unroll
        for (int o = 32; o; o >>= 1) s2 += __shfl_xor(s2, o);
        if ((tid & 63) == 0) red2[2 + (tid >> 6)] = s2;
    }
    __syncthreads();

    if (tid < EMB) {
        float var = (red2[2] + red2[3]) * (1.0f / (float)EMB);
        out[(size_t)bi * EMB + tid] = d / sqrtf(var + EPS_LN) * gamma[tid] + beta[tid];
    }
}

// -------------------------------------------------------------------------
extern "C" void kernel_launch(void* const* d_in, const int* in_sizes, int n_in,
                              void* d_out, int out_size, void* d_ws, size_t ws_size,
                              hipStream_t stream)
{
    const float* rbf    = (const float*)d_in[0];
    const float* r_hat  = (const float*)d_in[1];
    const float* mask   = (const float*)d_in[2];
    const float* w_rad  = (const float*)d_in[3];
    const float* b_rad  = (const float*)d_in[4];
    const float* w1     = (const float*)d_in[5];
    const float* b1     = (const float*)d_in[6];
    const float* w2     = (const float*)d_in[7];
    const float* b2     = (const float*)d_in[8];
    const float* gamma  = (const float*)d_in[9];
    const float* beta   = (const float*)d_in[10];
    float* out = (float*)d_out;

    float* w_ws = (float*)d_ws;   // B*N*N floats = 409600 bytes

    // K1: one wave per (b,i,j): B*N*N waves, 4 waves per 256-thread block
    const int n_out1  = B * N * N;
    const int blocks1 = (n_out1 + 3) / 4;
    radial_w_kernel<<<blocks1, 256, 0, stream>>>(rbf, mask, w_rad, b_rad, w_ws);

    // K2: one block per (b,i)
    agg_mlp_ln_kernel<<<B * N, 256, 0, stream>>>(r_hat, w_ws, w1, b1, w2, b2,
                                                 gamma, beta, out);
}

// Round 2
// 101.228 us; speedup vs baseline: 1.2421x; 1.2421x over previous
//
#include <hip/hip_runtime.h>
#include <math.h>

// Problem constants (from setup_inputs)
constexpr int B   = 4;
constexpr int N   = 160;
constexpr int R   = 64;
constexpr int EMB = 128;
constexpr int HID = 128;
constexpr float EPS_LN  = 1e-5f;
constexpr float CLIP_LO = -0.999999f;   // -1.0 + 1e-6
constexpr float CLIP_HI =  0.999999f;   //  1.0 - 1e-6
constexpr int NM = 23;  // 20 moment channels + 3 diagonal-clip corrections

// ---------------------------------------------------------------------------
// Fully fused: per (b,i) block computes
//   w_j   = sigmoid(rbf[b,i,j,:]·w_rad + b_rad) * mask[b,i,j]
//   agg_l = sum_{j,k} w_j w_k P_l(r_j·r_k)   (via moment-tensor factorization)
//   out   = LN(silu(agg@w1+b1)@w2^T + b2) * gamma + beta
//
// Moment factorization (exact algebra, x_jk = r_j·r_k):
//   S = Σ w_j ;  V = Σ w_j r ;  M = Σ w_j r⊗r ;  T = Σ w_j r⊗r⊗r
//   Σ ww      = S²
//   Σ ww x    = |V|²
//   Σ ww x²   = ‖M‖²_F            → agg2 = 1.5‖M‖² − 0.5 S²
//   Σ ww x³   = ‖T‖²              → agg3 = 2.5‖T‖² − 1.5 |V|²
// plus the diagonal correction for the reference's clip at ±(1−1e-6).
// ---------------------------------------------------------------------------
__global__ __launch_bounds__(256) void fused_threebody_kernel(
    const float* __restrict__ rbf,
    const float* __restrict__ r_hat,
    const float* __restrict__ mask,
    const float* __restrict__ w_rad,
    const float* __restrict__ b_rad,
    const float* __restrict__ w1,
    const float* __restrict__ b1,
    const float* __restrict__ w2,
    const float* __restrict__ b2,
    const float* __restrict__ gamma,
    const float* __restrict__ beta,
    float* __restrict__ out)
{
    __shared__ float wv[N], xs[N], ys[N], zs[N];
    __shared__ float redm[4][NM];
    __shared__ float hs[HID];
    __shared__ float red2[4];

    const int bi   = blockIdx.x;      // 0 .. B*N-1
    const int tid  = threadIdx.x;
    const int lane = tid & 63;
    const int wid  = tid >> 6;

    // ---- Phase 1a: stage r_hat row into LDS (SoA) ----
    const float* rh = r_hat + (size_t)bi * N * 3;
    for (int f = tid; f < N * 3; f += 256) {
        int j = f / 3, c = f - 3 * j;
        float val = rh[f];
        if (c == 0)      xs[j] = val;
        else if (c == 1) ys[j] = val;
        else             zs[j] = val;
    }

    // ---- Phase 1b: radial weights. Wave wid handles j in [wid*40, wid*40+40).
    // 4 rows per float4 load: 16 lanes cover the 64 R-channels of one row.
    const int rgroup = lane & 15;     // float4 slot within the row
    const int jsub   = lane >> 4;     // which of the 4 rows this lane serves
    const float4 wr4 = ((const float4*)w_rad)[rgroup];
    const float  brad = b_rad[0];
    const float* rbf_row = rbf + (size_t)bi * N * R;
    const float* mrow    = mask + (size_t)bi * N;

    #pragma unroll
    for (int it = 0; it < 10; ++it) {
        int j = wid * 40 + it * 4 + jsub;
        float4 v4 = ((const float4*)rbf_row)[j * (R / 4) + rgroup];
        float v = v4.x * wr4.x + v4.y * wr4.y + v4.z * wr4.z + v4.w * wr4.w;
        v += __shfl_xor(v, 1);
        v += __shfl_xor(v, 2);
        v += __shfl_xor(v, 4);
        v += __shfl_xor(v, 8);
        if (rgroup == 0) {
            float s = v + brad;
            wv[j] = (1.0f / (1.0f + expf(-s))) * mrow[j];
        }
    }
    __syncthreads();

    // ---- Phase 2: weighted moments (+ diagonal clip correction), j = tid ----
    float m[NM];
    #pragma unroll
    for (int q = 0; q < NM; ++q) m[q] = 0.f;
    if (tid < N) {
        const float w = wv[tid], x = xs[tid], y = ys[tid], z = zs[tid];
        const float wx = w * x, wy = w * y, wz = w * z;
        m[0] = w;
        m[1] = wx;        m[2] = wy;        m[3] = wz;
        m[4] = wx * x;    m[5] = wy * y;    m[6] = wz * z;
        m[7] = wx * y;    m[8] = wx * z;    m[9] = wy * z;
        m[10] = wx * x * x;  m[11] = wy * y * y;  m[12] = wz * z * z;
        m[13] = wx * x * y;  m[14] = wx * x * z;  m[15] = wx * y * y;
        m[16] = wy * y * z;  m[17] = wx * z * z;  m[18] = wy * z * z;
        m[19] = wx * y * z;
        // diagonal: moments used raw x_jj = |r_j|²; reference clips it.
        const float xd = x * x + y * y + z * z;
        const float xc = fminf(fmaxf(xd, CLIP_LO), CLIP_HI);
        const float p2c = (3.0f * xc * xc - 1.0f) * 0.5f;
        const float p3c = (5.0f * xc * p2c - 2.0f * xc) / 3.0f;
        const float p2r = 1.5f * xd * xd - 0.5f;
        const float p3r = 2.5f * xd * xd * xd - 1.5f * xd;
        const float ww = w * w;
        m[20] = ww * (xc - xd);
        m[21] = ww * (p2c - p2r);
        m[22] = ww * (p3c - p3r);
    }
    #pragma unroll
    for (int o = 32; o; o >>= 1) {
        #pragma unroll
        for (int q = 0; q < NM; ++q) m[q] += __shfl_xor(m[q], o);
    }
    if (lane == 0) {
        #pragma unroll
        for (int q = 0; q < NM; ++q) redm[wid][q] = m[q];
    }
    __syncthreads();

    // ---- Phase 3: finalize aggregates + MLP layer 1 (threads 0..127) ----
    if (tid < HID) {
        float sm[NM];
        #pragma unroll
        for (int q = 0; q < NM; ++q)
            sm[q] = redm[0][q] + redm[1][q] + redm[2][q] + redm[3][q];

        const float agg0 = sm[0] * sm[0];
        const float a1r  = sm[1] * sm[1] + sm[2] * sm[2] + sm[3] * sm[3];
        const float frob = sm[4] * sm[4] + sm[5] * sm[5] + sm[6] * sm[6]
                         + 2.f * (sm[7] * sm[7] + sm[8] * sm[8] + sm[9] * sm[9]);
        const float t2   = sm[10] * sm[10] + sm[11] * sm[11] + sm[12] * sm[12]
                         + 3.f * (sm[13] * sm[13] + sm[14] * sm[14] + sm[15] * sm[15]
                                + sm[16] * sm[16] + sm[17] * sm[17] + sm[18] * sm[18])
                         + 6.f * sm[19] * sm[19];
        const float agg2 = 1.5f * frob - 0.5f * agg0 + sm[21];
        const float agg3 = 2.5f * t2   - 1.5f * a1r  + sm[22];
        const float agg1 = a1r + sm[20];

        const float pre = b1[tid] + agg0 * w1[tid * 4 + 0] + agg1 * w1[tid * 4 + 1]
                                  + agg2 * w1[tid * 4 + 2] + agg3 * w1[tid * 4 + 3];
        hs[tid] = pre / (1.0f + expf(-pre));   // silu
    }
    __syncthreads();

    // ---- Phase 4: MLP layer 2 + LayerNorm (threads 0..127) ----
    float acc = 0.f;
    if (tid < EMB) {
        acc = b2[tid];
        const float4* w2r = (const float4*)(w2 + (size_t)tid * HID);
        #pragma unroll 8
        for (int h4 = 0; h4 < HID / 4; ++h4) {
            float4 wq = w2r[h4];
            float4 hq = *(const float4*)(hs + h4 * 4);
            acc += wq.x * hq.x + wq.y * hq.y + wq.z * hq.z + wq.w * hq.w;
        }
        float s = acc;
        #pragma unroll
        for (int o = 32; o; o >>= 1) s += __shfl_xor(s, o);
        if ((tid & 63) == 0) red2[tid >> 6] = s;
    }
    __syncthreads();

    const float mu = (red2[0] + red2[1]) * (1.0f / (float)EMB);
    const float d  = acc - mu;
    if (tid < EMB) {
        float s2 = d * d;
        #pragma unroll
        for (int o = 32; o; o >>= 1) s2 += __shfl_xor(s2, o);
        if ((tid & 63) == 0) red2[2 + (tid >> 6)] = s2;
    }
    __syncthreads();

    if (tid < EMB) {
        float var = (red2[2] + red2[3]) * (1.0f / (float)EMB);
        out[(size_t)bi * EMB + tid] = d / sqrtf(var + EPS_LN) * gamma[tid] + beta[tid];
    }
}

// ---------------------------------------------------------------------------
extern "C" void kernel_launch(void* const* d_in, const int* in_sizes, int n_in,
                              void* d_out, int out_size, void* d_ws, size_t ws_size,
                              hipStream_t stream)
{
    const float* rbf    = (const float*)d_in[0];
    const float* r_hat  = (const float*)d_in[1];
    const float* mask   = (const float*)d_in[2];
    const float* w_rad  = (const float*)d_in[3];
    const float* b_rad  = (const float*)d_in[4];
    const float* w1     = (const float*)d_in[5];
    const float* b1     = (const float*)d_in[6];
    const float* w2     = (const float*)d_in[7];
    const float* b2     = (const float*)d_in[8];
    const float* gamma  = (const float*)d_in[9];
    const float* beta   = (const float*)d_in[10];
    float* out = (float*)d_out;

    fused_threebody_kernel<<<B * N, 256, 0, stream>>>(
        rbf, r_hat, mask, w_rad, b_rad, w1, b1, w2, b2, gamma, beta, out);
}

// Round 3
// 99.969 us; speedup vs baseline: 1.2577x; 1.0126x over previous
//
#include <hip/hip_runtime.h>
#include <math.h>

// Problem constants (from setup_inputs)
constexpr int B   = 4;
constexpr int N   = 160;
constexpr int R   = 64;
constexpr int EMB = 128;
constexpr int HID = 128;
constexpr float EPS_LN  = 1e-5f;
constexpr float CLIP_LO = -0.999999f;   // -1.0 + 1e-6
constexpr float CLIP_HI =  0.999999f;   //  1.0 - 1e-6
constexpr int NM = 23;  // 20 moment channels + 3 diagonal-clip corrections

// ---------------------------------------------------------------------------
// Fully fused: per (b,i) block computes
//   w_j   = sigmoid(rbf[b,i,j,:]·w_rad + b_rad) * mask[b,i,j]
//   agg_l = sum_{j,k} w_j w_k P_l(r_j·r_k)   (via moment-tensor factorization)
//   out   = LN(silu(agg@w1+b1)@w2^T + b2) * gamma + beta
//
// Moment factorization (exact algebra, x_jk = r_j·r_k):
//   S = Σ w_j ;  V = Σ w_j r ;  M = Σ w_j r⊗r ;  T = Σ w_j r⊗r⊗r
//   Σ ww      = S²
//   Σ ww x    = |V|²
//   Σ ww x²   = ‖M‖²_F            → agg2 = 1.5‖M‖² − 0.5 S²
//   Σ ww x³   = ‖T‖²              → agg3 = 2.5‖T‖² − 1.5 |V|²
// plus the diagonal correction for the reference's clip at ±(1−1e-6).
//
// Mask-gating: 30% of access_mask is 0; those rows contribute w=0 exactly, so
// their 256B rbf rows are never loaded (exec-masked lanes fetch nothing).
// ---------------------------------------------------------------------------
__global__ __launch_bounds__(256) void fused_threebody_kernel(
    const float* __restrict__ rbf,
    const float* __restrict__ r_hat,
    const float* __restrict__ mask,
    const float* __restrict__ w_rad,
    const float* __restrict__ b_rad,
    const float* __restrict__ w1,
    const float* __restrict__ b1,
    const float* __restrict__ w2,
    const float* __restrict__ b2,
    const float* __restrict__ gamma,
    const float* __restrict__ beta,
    float* __restrict__ out)
{
    __shared__ float wv[N], xs[N], ys[N], zs[N];
    __shared__ float redm[4][NM];
    __shared__ float hs[HID];
    __shared__ float red2[4];

    const int bi   = blockIdx.x;      // 0 .. B*N-1
    const int tid  = threadIdx.x;
    const int lane = tid & 63;
    const int wid  = tid >> 6;

    // ---- Phase 1a: stage r_hat row into LDS (SoA) ----
    const float* rh = r_hat + (size_t)bi * N * 3;
    for (int f = tid; f < N * 3; f += 256) {
        int j = f / 3, c = f - 3 * j;
        float val = rh[f];
        if (c == 0)      xs[j] = val;
        else if (c == 1) ys[j] = val;
        else             zs[j] = val;
    }

    // ---- Phase 1b: radial weights. Wave wid handles j in [wid*40, wid*40+40).
    // 4 rows per float4 load: 16 lanes cover the 64 R-channels of one row.
    const int rgroup = lane & 15;     // float4 slot within the row
    const int jsub   = lane >> 4;     // which of the 4 rows this lane serves
    const float4 wr4 = ((const float4*)w_rad)[rgroup];
    const float  brad = b_rad[0];
    const float* rbf_row = rbf + (size_t)bi * N * R;
    const float* mrow    = mask + (size_t)bi * N;

    // (1) mask lookups (640B row, L2-resident after first block touches it)
    float mz[10];
    #pragma unroll
    for (int it = 0; it < 10; ++it)
        mz[it] = mrow[wid * 40 + it * 4 + jsub];

    // (2) predicated rbf loads — all 10 issued back-to-back, exec-masked
    float4 v4s[10];
    #pragma unroll
    for (int it = 0; it < 10; ++it) {
        int j = wid * 40 + it * 4 + jsub;
        float4 v4 = make_float4(0.f, 0.f, 0.f, 0.f);
        if (mz[it] != 0.0f)
            v4 = ((const float4*)rbf_row)[j * (R / 4) + rgroup];
        v4s[it] = v4;
    }

    // (3) dot + 16-lane reduce + sigmoid*mask
    #pragma unroll
    for (int it = 0; it < 10; ++it) {
        int j = wid * 40 + it * 4 + jsub;
        float v = v4s[it].x * wr4.x + v4s[it].y * wr4.y
                + v4s[it].z * wr4.z + v4s[it].w * wr4.w;
        v += __shfl_xor(v, 1);
        v += __shfl_xor(v, 2);
        v += __shfl_xor(v, 4);
        v += __shfl_xor(v, 8);
        if (rgroup == 0) {
            float s = v + brad;
            wv[j] = (mz[it] != 0.0f)
                      ? (1.0f / (1.0f + expf(-s))) * mz[it]
                      : 0.0f;
        }
    }
    __syncthreads();

    // ---- Phase 2: weighted moments (+ diagonal clip correction), j = tid ----
    float m[NM];
    #pragma unroll
    for (int q = 0; q < NM; ++q) m[q] = 0.f;
    if (tid < N) {
        const float w = wv[tid], x = xs[tid], y = ys[tid], z = zs[tid];
        const float wx = w * x, wy = w * y, wz = w * z;
        m[0] = w;
        m[1] = wx;        m[2] = wy;        m[3] = wz;
        m[4] = wx * x;    m[5] = wy * y;    m[6] = wz * z;
        m[7] = wx * y;    m[8] = wx * z;    m[9] = wy * z;
        m[10] = wx * x * x;  m[11] = wy * y * y;  m[12] = wz * z * z;
        m[13] = wx * x * y;  m[14] = wx * x * z;  m[15] = wx * y * y;
        m[16] = wy * y * z;  m[17] = wx * z * z;  m[18] = wy * z * z;
        m[19] = wx * y * z;
        // diagonal: moments used raw x_jj = |r_j|²; reference clips it.
        const float xd = x * x + y * y + z * z;
        const float xc = fminf(fmaxf(xd, CLIP_LO), CLIP_HI);
        const float p2c = (3.0f * xc * xc - 1.0f) * 0.5f;
        const float p3c = (5.0f * xc * p2c - 2.0f * xc) / 3.0f;
        const float p2r = 1.5f * xd * xd - 0.5f;
        const float p3r = 2.5f * xd * xd * xd - 1.5f * xd;
        const float ww = w * w;
        m[20] = ww * (xc - xd);
        m[21] = ww * (p2c - p2r);
        m[22] = ww * (p3c - p3r);
    }
    #pragma unroll
    for (int o = 32; o; o >>= 1) {
        #pragma unroll
        for (int q = 0; q < NM; ++q) m[q] += __shfl_xor(m[q], o);
    }
    if (lane == 0) {
        #pragma unroll
        for (int q = 0; q < NM; ++q) redm[wid][q] = m[q];
    }
    __syncthreads();

    // ---- Phase 3: finalize aggregates + MLP layer 1 (threads 0..127) ----
    if (tid < HID) {
        float sm[NM];
        #pragma unroll
        for (int q = 0; q < NM; ++q)
            sm[q] = redm[0][q] + redm[1][q] + redm[2][q] + redm[3][q];

        const float agg0 = sm[0] * sm[0];
        const float a1r  = sm[1] * sm[1] + sm[2] * sm[2] + sm[3] * sm[3];
        const float frob = sm[4] * sm[4] + sm[5] * sm[5] + sm[6] * sm[6]
                         + 2.f * (sm[7] * sm[7] + sm[8] * sm[8] + sm[9] * sm[9]);
        const float t2   = sm[10] * sm[10] + sm[11] * sm[11] + sm[12] * sm[12]
                         + 3.f * (sm[13] * sm[13] + sm[14] * sm[14] + sm[15] * sm[15]
                                + sm[16] * sm[16] + sm[17] * sm[17] + sm[18] * sm[18])
                         + 6.f * sm[19] * sm[19];
        const float agg2 = 1.5f * frob - 0.5f * agg0 + sm[21];
        const float agg3 = 2.5f * t2   - 1.5f * a1r  + sm[22];
        const float agg1 = a1r + sm[20];

        const float pre = b1[tid] + agg0 * w1[tid * 4 + 0] + agg1 * w1[tid * 4 + 1]
                                  + agg2 * w1[tid * 4 + 2] + agg3 * w1[tid * 4 + 3];
        hs[tid] = pre / (1.0f + expf(-pre));   // silu
    }
    __syncthreads();

    // ---- Phase 4: MLP layer 2 + LayerNorm (threads 0..127) ----
    float acc = 0.f;
    if (tid < EMB) {
        acc = b2[tid];
        const float4* w2r = (const float4*)(w2 + (size_t)tid * HID);
        #pragma unroll 8
        for (int h4 = 0; h4 < HID / 4; ++h4) {
            float4 wq = w2r[h4];
            float4 hq = *(const float4*)(hs + h4 * 4);
            acc += wq.x * hq.x + wq.y * hq.y + wq.z * hq.z + wq.w * hq.w;
        }
        float s = acc;
        #pragma unroll
        for (int o = 32; o; o >>= 1) s += __shfl_xor(s, o);
        if ((tid & 63) == 0) red2[tid >> 6] = s;
    }
    __syncthreads();

    const float mu = (red2[0] + red2[1]) * (1.0f / (float)EMB);
    const float d  = acc - mu;
    if (tid < EMB) {
        float s2 = d * d;
        #pragma unroll
        for (int o = 32; o; o >>= 1) s2 += __shfl_xor(s2, o);
        if ((tid & 63) == 0) red2[2 + (tid >> 6)] = s2;
    }
    __syncthreads();

    if (tid < EMB) {
        float var = (red2[2] + red2[3]) * (1.0f / (float)EMB);
        out[(size_t)bi * EMB + tid] = d / sqrtf(var + EPS_LN) * gamma[tid] + beta[tid];
    }
}

// ---------------------------------------------------------------------------
extern "C" void kernel_launch(void* const* d_in, const int* in_sizes, int n_in,
                              void* d_out, int out_size, void* d_ws, size_t ws_size,
                              hipStream_t stream)
{
    const float* rbf    = (const float*)d_in[0];
    const float* r_hat  = (const float*)d_in[1];
    const float* mask   = (const float*)d_in[2];
    const float* w_rad  = (const float*)d_in[3];
    const float* b_rad  = (const float*)d_in[4];
    const float* w1     = (const float*)d_in[5];
    const float* b1     = (const float*)d_in[6];
    const float* w2     = (const float*)d_in[7];
    const float* b2     = (const float*)d_in[8];
    const float* gamma  = (const float*)d_in[9];
    const float* beta   = (const float*)d_in[10];
    float* out = (float*)d_out;

    fused_threebody_kernel<<<B * N, 256, 0, stream>>>(
        rbf, r_hat, mask, w_rad, b_rad, w1, b1, w2, b2, gamma, beta, out);
}